// Round 6
// baseline (821.289 us; speedup 1.0000x reference)
//
#include <hip/hip_runtime.h>

typedef unsigned short u16;
typedef unsigned int u32;

using short8 = __attribute__((ext_vector_type(8))) short;
using f32x4  = __attribute__((ext_vector_type(4))) float;

#define LOG2E 1.44269504088896340736f

// X1 row (per batch): [h1_hi 0:128 | h1_lo 128:256 | x 256:272 | zeros 272:288 | pad]
#define X1S 296
// H2 row: [h2_hi 0:64 | h2_lo 64:128 | pad]
#define H2S 136
#define DBS 40

__device__ __forceinline__ u16 f2bf(float f) {
  u32 u = __float_as_uint(f);
  return (u16)((u + 0x7FFFu + ((u >> 16) & 1u)) >> 16);
}
__device__ __forceinline__ float bf2f(u16 h) {
  return __uint_as_float(((u32)h) << 16);
}
__device__ __forceinline__ float sigm(float x) {
  return __builtin_amdgcn_rcpf(1.0f + __builtin_amdgcn_exp2f(-LOG2E * x));
}
__device__ __forceinline__ float tanh_(float x) {
  return 1.0f - 2.0f * __builtin_amdgcn_rcpf(1.0f + __builtin_amdgcn_exp2f(2.0f * LOG2E * x));
}
__device__ __forceinline__ f32x4 mfma_(short8 a, short8 b, f32x4 c) {
  return __builtin_amdgcn_mfma_f32_16x16x32_bf16(a, b, c, 0, 0, 0);
}

// 256 threads, 1 wave/SIMD (the only config confirmed to give the full VGPR
// budget). Skewed pipeline: iter t = elem(L2 step t-1) + elem(L1 step t),
// ONE barrier, then MFMA-issue for L2(t) and L1(t+1) which drain under the
// next iteration's elementwise VALU.
__global__ __launch_bounds__(256, 1) void spc_lstm(
    const float* __restrict__ xh,   const float* __restrict__ xfr,
    const float* __restrict__ Wih1, const float* __restrict__ Whh1,
    const float* __restrict__ bih1, const float* __restrict__ bhh1,
    const float* __restrict__ Wih2, const float* __restrict__ Whh2,
    const float* __restrict__ bih2, const float* __restrict__ bhh2,
    const float* __restrict__ Wd,   const float* __restrict__ bd,
    const float* __restrict__ Wf,   const float* __restrict__ bfv,
    const float* __restrict__ ob,   float* __restrict__ out)
{
  __shared__ __align__(16) u16 X1[2][16 * X1S];   // h1 double buffer (+x slot)
  __shared__ __align__(16) u16 H2B[2][16 * H2S];  // h2 double buffer
  __shared__ __align__(16) u16 DB[16 * DBS];
  __shared__ __align__(16) u16 W1xF[32 * 512];    // Wih1 x-frags (zeros k>=16)
  __shared__ __align__(16) u16 W2F[64 * 512];     // Wih2 frags
  __shared__ __align__(16) u16 WdF[4 * 512];
  __shared__ __align__(16) u16 WfF[512];          // zeros n>=2
  __shared__ u16 PREDV[16][2];

  const int tid = threadIdx.x;
  const int w   = tid >> 6;
  const int l   = tid & 63;
  const int c   = l & 15;
  const int q   = l >> 4;
  const int bb  = blockIdx.x << 4;

  short8 w1h[8][4];   // Whh1 (128 VGPR)
  short8 w2h[4][2];   // Whh2 (32 VGPR)
  float  b1r[8], b2r[4];

  // ---- zero activation LDS ----
  for (int i = tid; i < 2 * 16 * X1S; i += 256) ((u16*)X1)[i] = 0;
  for (int i = tid; i < 2 * 16 * H2S; i += 256) ((u16*)H2B)[i] = 0;
  for (int i = tid; i < 16 * DBS; i += 256) DB[i] = 0;
  if (tid < 32) ((u16*)PREDV)[tid] = 0;
  __syncthreads();

  // ---- weight LDS fills (fragment-linear: (k,n) -> ((k>>3)*16+n)*8 + (k&7)) ----
  for (int i = tid; i < 64 * 512; i += 256) {
    const int rid = i >> 9, e = i & 511, k = e >> 4, n = e & 15;
    const int ww = rid >> 4, nt = (rid >> 2) & 3, kc = rid & 3;
    const int g = nt * 64 + ww * 16 + n;
    W2F[rid * 512 + ((k >> 3) * 16 + n) * 8 + (k & 7)] = f2bf(Wih2[g * 128 + kc * 32 + k]);
  }
  for (int i = tid; i < 32 * 512; i += 256) {
    const int tix = i >> 9, e = i & 511, k = e >> 4, n = e & 15;
    const int ww = tix >> 3, nt = tix & 7;
    const int g = (nt >> 1) * 128 + ww * 32 + (nt & 1) * 16 + n;
    W1xF[tix * 512 + ((k >> 3) * 16 + n) * 8 + (k & 7)] =
        (k < 16) ? f2bf(Wih1[g * 16 + k]) : (u16)0;
  }
  for (int i = tid; i < 4 * 512; i += 256) {
    const int tix = i >> 9, e = i & 511, k = e >> 4, n = e & 15;
    const int ww = tix >> 1, kc2 = tix & 1;
    WdF[tix * 512 + ((k >> 3) * 16 + n) * 8 + (k & 7)] =
        f2bf(Wd[(ww * 16 + n) * 64 + kc2 * 32 + k]);
  }
  for (int i = tid; i < 512; i += 256) {
    const int k = i >> 4, n = i & 15;
    WfF[((k >> 3) * 16 + n) * 8 + (k & 7)] = (n < 2) ? f2bf(Wf[n * 32 + k]) : (u16)0;
  }

  // ---- register weights / biases ----
  #pragma unroll
  for (int nt = 0; nt < 8; nt++) {
    const int g = (nt >> 1) * 128 + w * 32 + (nt & 1) * 16 + c;
    b1r[nt] = bih1[g] + bhh1[g];
    #pragma unroll
    for (int kc = 0; kc < 4; kc++) {
      short8 v;
      #pragma unroll
      for (int j = 0; j < 8; j++)
        v[j] = (short)f2bf(Whh1[g * 128 + kc * 32 + q * 8 + j]);
      w1h[nt][kc] = v;
    }
  }
  #pragma unroll
  for (int nt = 0; nt < 4; nt++) {
    const int g = nt * 64 + w * 16 + c;
    b2r[nt] = bih2[g] + bhh2[g];
    #pragma unroll
    for (int kc = 0; kc < 2; kc++) {
      short8 v;
      #pragma unroll
      for (int j = 0; j < 8; j++)
        v[j] = (short)f2bf(Whh2[g * 64 + kc * 32 + q * 8 + j]);
      w2h[nt][kc] = v;
    }
  }
  const float bdr = (w < 2) ? bd[w * 16 + c] : 0.f;
  const float bfr = (w == 0 && c < 2) ? (bfv[c] + ob[c]) : 0.f;

  // ---- stage x(0) -> X1[0].xslot; prime xreg = x(1) ----
  const int xr = tid >> 4, xcc = tid & 15;
  X1[0][xr * X1S + 256 + xcc] = f2bf(xh[(bb + xr) * 3200 + xcc]);
  float xreg = xh[(bb + xr) * 3200 + 16 + xcc];
  bool  dreg = true;

  f32x4 c1[2]; f32x4 c2;
  c1[0] = (f32x4){0,0,0,0}; c1[1] = (f32x4){0,0,0,0}; c2 = (f32x4){0,0,0,0};
  __syncthreads();

  // ---- prologue: acc1 = L1 preacts(0) = bias + Wih1@x(0) (h=0 terms are exact zeros) ----
  f32x4 acc1[8]; f32x4 acc2[4];
  {
    const short8 ax = *(const short8*)&X1[0][c * X1S + 256 + q * 8];
    #pragma unroll
    for (int nt = 0; nt < 8; nt++) {
      acc1[nt] = (f32x4){b1r[nt], b1r[nt], b1r[nt], b1r[nt]};
      const short8 wxv = *(const short8*)&W1xF[(w * 8 + nt) * 512 + l * 8];
      acc1[nt] = mfma_(ax, wxv, acc1[nt]);
    }
  }
  #pragma unroll
  for (int nt = 0; nt < 4; nt++) acc2[nt] = (f32x4){0,0,0,0};

  // L1 elementwise (consumes acc1 -> h1(t) into Xcur)
  auto l1elem = [&](u16* Xcur) {
    #pragma unroll
    for (int sub = 0; sub < 2; sub++) {
      const int u = w * 32 + sub * 16 + c;
      #pragma unroll
      for (int r = 0; r < 4; r++) {
        float ig = sigm(acc1[sub][r]);
        float fg = sigm(acc1[2 + sub][r]);
        float gg = tanh_(acc1[4 + sub][r]);
        float og = sigm(acc1[6 + sub][r]);
        float cn = fg * c1[sub][r] + ig * gg;
        float hn = og * tanh_(cn);
        c1[sub][r] = cn;
        u16 hi = f2bf(hn);
        float lo = hn - bf2f(hi);
        const int row = (q * 4 + r) * X1S;
        Xcur[row + u]       = hi;
        Xcur[row + 128 + u] = f2bf(lo);
      }
    }
  };

  // ==== skewed loop: iter t = elem(L2 t-1) + elem(L1 t); bar; MFMA L2(t), L1(t+1) ====
  for (int t = 0; t <= 220; t++) {
    const int pc = t & 1;
    u16* Xcur = X1[pc];        // h1(t) dest; x(t) src
    u16* Xoth = X1[pc ^ 1];    // x(t+1) stage dest; h1(t-1) (already consumed)
    u16* Hdst = H2B[pc ^ 1];   // h2(t-1) dest
    const bool dec = (t >= 201);

    // ---- A: L2 elementwise for step t-1 ----
    if (t >= 1) {
      const int u = w * 16 + c;
      #pragma unroll
      for (int r = 0; r < 4; r++) {
        float ig = sigm(acc2[0][r]);
        float fg = sigm(acc2[1][r]);
        float gg = tanh_(acc2[2][r]);
        float og = sigm(acc2[3][r]);
        float cn = fg * c2[r] + ig * gg;
        float hn = og * tanh_(cn);
        c2[r] = cn;
        u16 hi = f2bf(hn);
        float lo = hn - bf2f(hi);
        const int row = (q * 4 + r) * H2S;
        Hdst[row + u]      = hi;
        Hdst[row + 64 + u] = f2bf(lo);
      }
    }

    // ---- stage x(t+1) -> Xoth.xslot; issue load of x(t+2) ----
    const float xw = xreg; const bool dw = dreg;
    {
      const int s2 = t + 2;
      dreg = false;
      if (s2 < 200) { xreg = xh[(bb + xr) * 3200 + s2 * 16 + xcc]; dreg = true; }
      else if (s2 < 220) {
        const int s = s2 - 200;
        if (xcc < 14)    { xreg = xfr[(bb + xr) * 280 + s * 14 + xcc]; dreg = true; }
        else if (s == 0) { xreg = xh[(bb + xr) * 3200 + 199 * 16 + xcc]; dreg = true; }
      }
    }
    if (dw) Xoth[xr * X1S + 256 + xcc] = f2bf(xw);

    if (!dec) {
      // encoder: acc1 is complete (x-part was issued last iter)
      l1elem(Xcur);
      __syncthreads();                    // publish h1(t), h2(t-1), x(t+1)
    } else {
      __syncthreads();                    // #1: h2(t-1) published
      if (w < 2) {                        // head: d(t-1) = relu(Wd @ h2(t-1) + bd)
        f32x4 accd = (f32x4){bdr, bdr, bdr, bdr};
        #pragma unroll
        for (int kc = 0; kc < 4; kc++) {
          const short8 ad  = *(const short8*)&Hdst[c * H2S + kc * 32 + q * 8];
          const short8 wdk = *(const short8*)&WdF[(w * 2 + (kc & 1)) * 512 + l * 8];
          accd = mfma_(ad, wdk, accd);
        }
        #pragma unroll
        for (int r = 0; r < 4; r++)
          DB[(q * 4 + r) * DBS + w * 16 + c] = f2bf(fmaxf(accd[r], 0.f));
      }
      __syncthreads();                    // #2: d published
      if (w == 0) {                       // pred(t-1) = Wf @ d + bf + ob
        const short8 ap  = *(const short8*)&DB[c * DBS + q * 8];
        const short8 wfv = *(const short8*)&WfF[l * 8];
        f32x4 accp = (f32x4){bfr, bfr, bfr, bfr};
        accp = mfma_(ap, wfv, accp);
        if (c < 2) {
          #pragma unroll
          for (int r = 0; r < 4; r++) {
            const int b = q * 4 + r;
            out[(bb + b) * 40 + (t - 1 - 200) * 2 + c] = accp[r];
            PREDV[b][c] = f2bf(accp[r]);
          }
        }
      }
      __syncthreads();                    // #3: pred published
      if (t <= 219) {
        // deferred x-part of L1(t), with pred feedback patch (feats 14,15)
        short8 ax = *(const short8*)&Xcur[c * X1S + 256 + q * 8];
        if (q == 1) {
          ax[6] = (short)PREDV[c][0];
          ax[7] = (short)PREDV[c][1];
        }
        #pragma unroll
        for (int nt = 0; nt < 8; nt++) {
          const short8 wxv = *(const short8*)&W1xF[(w * 8 + nt) * 512 + l * 8];
          acc1[nt] = mfma_(ax, wxv, acc1[nt]);
        }
        l1elem(Xcur);
      }
      __syncthreads();                    // #4: h1(t) published
    }

    // ---- K: MFMA issue. L2(t) first (consumed first next iter), then L1(t+1). ----
    if (t <= 219) {
      short8 fh[8];                       // h1(t) hi(0..3) + lo(4..7), shared by L2 and L1
      #pragma unroll
      for (int kc = 0; kc < 4; kc++) {
        fh[kc]     = *(const short8*)&Xcur[c * X1S + kc * 32 + q * 8];
        fh[4 + kc] = *(const short8*)&Xcur[c * X1S + 128 + kc * 32 + q * 8];
      }
      // L2(t): bias -> Wih2(hi,lo) -> Whh2(hi,lo)
      #pragma unroll
      for (int nt = 0; nt < 4; nt++)
        acc2[nt] = (f32x4){b2r[nt], b2r[nt], b2r[nt], b2r[nt]};
      #pragma unroll
      for (int kc = 0; kc < 4; kc++) {
        #pragma unroll
        for (int nt = 0; nt < 4; nt++) {
          const short8 wf_ = *(const short8*)&W2F[(w * 16 + nt * 4 + kc) * 512 + l * 8];
          acc2[nt] = mfma_(fh[kc],     wf_, acc2[nt]);
          acc2[nt] = mfma_(fh[4 + kc], wf_, acc2[nt]);
        }
      }
      #pragma unroll
      for (int kc = 0; kc < 2; kc++) {
        const short8 hhi = *(const short8*)&Hdst[c * H2S + kc * 32 + q * 8];
        const short8 hlo = *(const short8*)&Hdst[c * H2S + 64 + kc * 32 + q * 8];
        #pragma unroll
        for (int nt = 0; nt < 4; nt++) {
          acc2[nt] = mfma_(hhi, w2h[nt][kc], acc2[nt]);
          acc2[nt] = mfma_(hlo, w2h[nt][kc], acc2[nt]);
        }
      }
      // L1(t+1) h-part: bias -> Whh1(hi,lo); x-part only while x(t+1) is complete
      if (t <= 218) {
        #pragma unroll
        for (int nt = 0; nt < 8; nt++)
          acc1[nt] = (f32x4){b1r[nt], b1r[nt], b1r[nt], b1r[nt]};
        #pragma unroll
        for (int kc = 0; kc < 4; kc++) {
          #pragma unroll
          for (int nt = 0; nt < 8; nt++) {
            acc1[nt] = mfma_(fh[kc],     w1h[nt][kc], acc1[nt]);
            acc1[nt] = mfma_(fh[4 + kc], w1h[nt][kc], acc1[nt]);
          }
        }
        if (t + 1 <= 200) {
          const short8 ax = *(const short8*)&Xoth[c * X1S + 256 + q * 8];  // x(t+1)
          #pragma unroll
          for (int nt = 0; nt < 8; nt++) {
            const short8 wxv = *(const short8*)&W1xF[(w * 8 + nt) * 512 + l * 8];
            acc1[nt] = mfma_(ax, wxv, acc1[nt]);
          }
        }
      }
    }
  }
}

extern "C" void kernel_launch(void* const* d_in, const int* in_sizes, int n_in,
                              void* d_out, int out_size, void* d_ws, size_t ws_size,
                              hipStream_t stream) {
  (void)in_sizes; (void)n_in; (void)out_size; (void)d_ws; (void)ws_size;
  spc_lstm<<<dim3(256), dim3(256), 0, stream>>>(
      (const float*)d_in[0],  (const float*)d_in[1],
      (const float*)d_in[2],  (const float*)d_in[3],
      (const float*)d_in[4],  (const float*)d_in[5],
      (const float*)d_in[6],  (const float*)d_in[7],
      (const float*)d_in[8],  (const float*)d_in[9],
      (const float*)d_in[10], (const float*)d_in[11],
      (const float*)d_in[12], (const float*)d_in[13],
      (const float*)d_in[14], (float*)d_out);
}

// Round 7
// 590.421 us; speedup vs baseline: 1.3910x; 1.3910x over previous
//
#include <hip/hip_runtime.h>

typedef unsigned short u16;
typedef unsigned int u32;

using short8 = __attribute__((ext_vector_type(8))) short;
using f32x4  = __attribute__((ext_vector_type(4))) float;

#define LOG2E 1.44269504088896340736f

// X1 row (per batch): [h1_hi 0:128 | h1_lo 128:256 | x 256:272 | zeros 272:288 | pad]
#define X1S 296
// H2 row: [h2_hi 0:64 | h2_lo 64:128 | pad]
#define H2S 136
#define DBS 40

__device__ __forceinline__ u16 f2bf(float f) {
  u32 u = __float_as_uint(f);
  return (u16)((u + 0x7FFFu + ((u >> 16) & 1u)) >> 16);
}
__device__ __forceinline__ float bf2f(u16 h) {
  return __uint_as_float(((u32)h) << 16);
}
__device__ __forceinline__ float sigm(float x) {
  return __builtin_amdgcn_rcpf(1.0f + __builtin_amdgcn_exp2f(-LOG2E * x));
}
__device__ __forceinline__ float tanh_(float x) {
  return 1.0f - 2.0f * __builtin_amdgcn_rcpf(1.0f + __builtin_amdgcn_exp2f(2.0f * LOG2E * x));
}
__device__ __forceinline__ f32x4 mfma_(short8 a, short8 b, f32x4 c) {
  return __builtin_amdgcn_mfma_f32_16x16x32_bf16(a, b, c, 0, 0, 0);
}

// 512 threads (8 waves, 2 waves/SIMD) so MFMA issue and VALU from paired waves
// co-schedule (m114). Gate-split: each wave owns 16 L1 units (Whh1 = 64 VGPR);
// waves 0-3 also own 16 L2 units (Whh2 from LDS); waves 4-7 stage x + head.
// L2 lags L1 by one step -> one barrier per encoder step.
__global__ __launch_bounds__(512, 1) void spc_lstm(
    const float* __restrict__ xh,   const float* __restrict__ xfr,
    const float* __restrict__ Wih1, const float* __restrict__ Whh1,
    const float* __restrict__ bih1, const float* __restrict__ bhh1,
    const float* __restrict__ Wih2, const float* __restrict__ Whh2,
    const float* __restrict__ bih2, const float* __restrict__ bhh2,
    const float* __restrict__ Wd,   const float* __restrict__ bd,
    const float* __restrict__ Wf,   const float* __restrict__ bfv,
    const float* __restrict__ ob,   float* __restrict__ out)
{
  __shared__ __align__(16) u16 X1[2][16 * X1S];   // 18944 B
  __shared__ __align__(16) u16 H2B[2][16 * H2S];  //  8704 B
  __shared__ __align__(16) u16 DB[16 * DBS];      //  1280 B
  __shared__ __align__(16) u16 W1xF[32 * 256];    // 16384 B (k<16 only; k>=16 zero-frag)
  __shared__ __align__(16) u16 W2F[64 * 512];     // 65536 B Wih2
  __shared__ __align__(16) u16 Wh2F[32 * 512];    // 32768 B Whh2
  __shared__ __align__(16) u16 WdF[4 * 512];      //  4096 B
  __shared__ __align__(16) u16 WfF[512];          //  1024 B
  __shared__ u16 PREDV[16][2];
  // total ~148.8 KB

  const int tid = threadIdx.x;
  const int wv  = tid >> 6;          // 0..7
  const int l   = tid & 63;
  const int c   = l & 15;
  const int q   = l >> 4;
  const int bb  = blockIdx.x << 4;
  const bool isA = (wv < 4);

  short8 w1h[4][4];                  // Whh1 frags for this wave's 16 units (64 VGPR)
  float  b1r[4];
  float  b2r[4] = {0.f, 0.f, 0.f, 0.f};

  // ---- zero activation LDS ----
  for (int i = tid; i < 2 * 16 * X1S; i += 512) ((u16*)X1)[i] = 0;
  for (int i = tid; i < 2 * 16 * H2S; i += 512) ((u16*)H2B)[i] = 0;
  for (int i = tid; i < 16 * DBS; i += 512) DB[i] = 0;
  if (tid < 32) ((u16*)PREDV)[tid] = 0;
  __syncthreads();

  // ---- weight LDS fills (fragment-linear: (k,n) -> ((k>>3)*16+n)*8 + (k&7)) ----
  for (int i = tid; i < 64 * 512; i += 512) {         // Wih2 tiles (w, ty, kc)
    const int rid = i >> 9, e = i & 511, k = e >> 4, n = e & 15;
    const int ww = rid >> 4, ty = (rid >> 2) & 3, kc = rid & 3;
    const int g = ty * 64 + ww * 16 + n;
    W2F[rid * 512 + ((k >> 3) * 16 + n) * 8 + (k & 7)] = f2bf(Wih2[g * 128 + kc * 32 + k]);
  }
  for (int i = tid; i < 32 * 512; i += 512) {         // Whh2 tiles (w, ty, kc)
    const int tix = i >> 9, e = i & 511, k = e >> 4, n = e & 15;
    const int ww = tix >> 3, ty = (tix >> 1) & 3, kc = tix & 1;
    const int g = ty * 64 + ww * 16 + n;
    Wh2F[tix * 512 + ((k >> 3) * 16 + n) * 8 + (k & 7)] = f2bf(Whh2[g * 64 + kc * 32 + k]);
  }
  for (int i = tid; i < 32 * 256; i += 512) {         // Wih1 x-frags, tiles T = ty*8+uv
    const int T = i >> 8, e = i & 255, k = e >> 4, n = e & 15;
    const int ty = T >> 3, uv = T & 7;
    const int g = ty * 128 + uv * 16 + n;
    W1xF[T * 256 + ((k >> 3) * 16 + n) * 8 + (k & 7)] = f2bf(Wih1[g * 16 + k]);
  }
  for (int i = tid; i < 4 * 512; i += 512) {          // Wd tiles (ww, kc2)
    const int tix = i >> 9, e = i & 511, k = e >> 4, n = e & 15;
    const int ww = tix >> 1, kc2 = tix & 1;
    WdF[tix * 512 + ((k >> 3) * 16 + n) * 8 + (k & 7)] =
        f2bf(Wd[(ww * 16 + n) * 64 + kc2 * 32 + k]);
  }
  {                                                   // Wf (zeros n>=2)
    const int k = tid >> 4, n = tid & 15;
    if (tid < 512)
      WfF[((k >> 3) * 16 + n) * 8 + (k & 7)] = (n < 2) ? f2bf(Wf[n * 32 + k]) : (u16)0;
  }

  // ---- register weights / biases (wave wv owns L1 units wv*16+c) ----
  #pragma unroll
  for (int ty = 0; ty < 4; ty++) {
    const int g = ty * 128 + wv * 16 + c;
    b1r[ty] = bih1[g] + bhh1[g];
    #pragma unroll
    for (int kc = 0; kc < 4; kc++) {
      short8 v;
      #pragma unroll
      for (int j = 0; j < 8; j++)
        v[j] = (short)f2bf(Whh1[g * 128 + kc * 32 + q * 8 + j]);
      w1h[ty][kc] = v;
    }
  }
  if (isA) {
    #pragma unroll
    for (int ty = 0; ty < 4; ty++) {
      const int g = ty * 64 + wv * 16 + c;
      b2r[ty] = bih2[g] + bhh2[g];
    }
  }
  const float bdr = (wv == 4 || wv == 5) ? bd[(wv - 4) * 16 + c] : 0.f;
  const float bfr = (wv == 4 && c < 2) ? (bfv[c] + ob[c]) : 0.f;

  // ---- x staging (waves 4-7): stage x(0), prime x(1) ----
  const int xi = tid - 256, xr = (xi >> 4) & 15, xcc = xi & 15;
  float xreg = 0.f; bool dreg = false;
  if (!isA) {
    X1[0][xr * X1S + 256 + xcc] = f2bf(xh[(bb + xr) * 3200 + xcc]);
    xreg = xh[(bb + xr) * 3200 + 16 + xcc]; dreg = true;
  }
  f32x4 c1 = (f32x4){0,0,0,0};
  f32x4 c2 = (f32x4){0,0,0,0};
  __syncthreads();

  // ==== loop: iter t = [waves 0-3: L2(t-1)] + [all: L1(t)]; 1 barrier (enc) ====
  for (int t = 0; t <= 220; t++) {
    u16* Xc    = X1[t & 1];        // h1(t-1) hi/lo + x(t)
    u16* Xn    = X1[(t + 1) & 1];  // h1(t) dest, x(t+1) stage
    u16* Hprev = H2B[t & 1];       // h2(t-2)
    u16* Hdst  = H2B[(t + 1) & 1]; // h2(t-1) dest
    const bool dec = (t >= 201);

    // ---- Phase 2 (waves 0-3): L2 for step t-1 ----
    if (isA && t >= 1) {
      f32x4 acc2[4];
      #pragma unroll
      for (int ty = 0; ty < 4; ty++)
        acc2[ty] = (f32x4){b2r[ty], b2r[ty], b2r[ty], b2r[ty]};
      #pragma unroll
      for (int kc = 0; kc < 4; kc++) {
        const short8 fhi = *(const short8*)&Xc[c * X1S + kc * 32 + q * 8];
        const short8 flo = *(const short8*)&Xc[c * X1S + 128 + kc * 32 + q * 8];
        #pragma unroll
        for (int ty = 0; ty < 4; ty++) {
          const short8 wf_ = *(const short8*)&W2F[(wv * 16 + ty * 4 + kc) * 512 + l * 8];
          acc2[ty] = mfma_(fhi, wf_, acc2[ty]);
          acc2[ty] = mfma_(flo, wf_, acc2[ty]);
        }
      }
      #pragma unroll
      for (int kc = 0; kc < 2; kc++) {
        const short8 hhi = *(const short8*)&Hprev[c * H2S + kc * 32 + q * 8];
        const short8 hlo = *(const short8*)&Hprev[c * H2S + 64 + kc * 32 + q * 8];
        #pragma unroll
        for (int ty = 0; ty < 4; ty++) {
          const short8 wh_ = *(const short8*)&Wh2F[((wv * 4 + ty) * 2 + kc) * 512 + l * 8];
          acc2[ty] = mfma_(hhi, wh_, acc2[ty]);
          acc2[ty] = mfma_(hlo, wh_, acc2[ty]);
        }
      }
      const int u = wv * 16 + c;
      #pragma unroll
      for (int r = 0; r < 4; r++) {
        float ig = sigm(acc2[0][r]);
        float fg = sigm(acc2[1][r]);
        float gg = tanh_(acc2[2][r]);
        float og = sigm(acc2[3][r]);
        float cn = fg * c2[r] + ig * gg;
        float hn = og * tanh_(cn);
        c2[r] = cn;
        u16 hi = f2bf(hn);
        float lo = hn - bf2f(hi);
        const int row = (q * 4 + r) * H2S;
        Hdst[row + u]      = hi;
        Hdst[row + 64 + u] = f2bf(lo);
      }
    }

    // ---- x staging (waves 4-7): stage x(t+1), prefetch x(t+2) ----
    if (!isA) {
      const float xw = xreg; const bool dw = dreg;
      const int s2 = t + 2;
      dreg = false;
      if (s2 < 200) { xreg = xh[(bb + xr) * 3200 + s2 * 16 + xcc]; dreg = true; }
      else if (s2 < 220) {
        const int s = s2 - 200;
        if (xcc < 14)    { xreg = xfr[(bb + xr) * 280 + s * 14 + xcc]; dreg = true; }
        else if (s == 0) { xreg = xh[(bb + xr) * 3200 + 199 * 16 + xcc]; dreg = true; }
      }
      if (dw) Xn[xr * X1S + 256 + xcc] = f2bf(xw);
    }

    // ---- decoder head (waves 4,5 Wd; wave 4 Wf) ----
    if (dec) {
      __syncthreads();                 // #1: h2(t-1) visible
      if (wv == 4 || wv == 5) {
        const int ww = wv - 4;
        f32x4 accd = (f32x4){bdr, bdr, bdr, bdr};
        #pragma unroll
        for (int kc = 0; kc < 4; kc++) {
          const short8 ad  = *(const short8*)&Hdst[c * H2S + kc * 32 + q * 8];
          const short8 wdk = *(const short8*)&WdF[(ww * 2 + (kc & 1)) * 512 + l * 8];
          accd = mfma_(ad, wdk, accd);
        }
        #pragma unroll
        for (int r = 0; r < 4; r++)
          DB[(q * 4 + r) * DBS + ww * 16 + c] = f2bf(fmaxf(accd[r], 0.f));
      }
      __syncthreads();                 // #2: d visible
      if (wv == 4) {
        const short8 ap  = *(const short8*)&DB[c * DBS + q * 8];
        const short8 wfv = *(const short8*)&WfF[l * 8];
        f32x4 accp = (f32x4){bfr, bfr, bfr, bfr};
        accp = mfma_(ap, wfv, accp);
        if (c < 2) {
          #pragma unroll
          for (int r = 0; r < 4; r++) {
            const int b = q * 4 + r;
            out[(bb + b) * 40 + (t - 201) * 2 + c] = accp[r];
            PREDV[b][c] = f2bf(accp[r]);
          }
        }
      }
      __syncthreads();                 // #3: pred visible
    }

    // ---- Phase 1 (all waves): L1(t) ----
    if (t <= 219) {
      f32x4 acc1[4];
      #pragma unroll
      for (int ty = 0; ty < 4; ty++)
        acc1[ty] = (f32x4){b1r[ty], b1r[ty], b1r[ty], b1r[ty]};
      #pragma unroll
      for (int kc = 0; kc < 4; kc++) {
        const short8 ahi = *(const short8*)&Xc[c * X1S + kc * 32 + q * 8];
        const short8 alo = *(const short8*)&Xc[c * X1S + 128 + kc * 32 + q * 8];
        #pragma unroll
        for (int ty = 0; ty < 4; ty++) {
          acc1[ty] = mfma_(ahi, w1h[ty][kc], acc1[ty]);
          acc1[ty] = mfma_(alo, w1h[ty][kc], acc1[ty]);
        }
      }
      {
        short8 ax = *(const short8*)&Xc[c * X1S + 256 + q * 8];
        if (dec && q == 1) {           // pred feedback: features 14,15
          ax[6] = (short)PREDV[c][0];
          ax[7] = (short)PREDV[c][1];
        }
        #pragma unroll
        for (int ty = 0; ty < 4; ty++) {
          short8 wxv = (short8){0,0,0,0,0,0,0,0};
          if (q < 2)
            wxv = *(const short8*)&W1xF[(ty * 8 + wv) * 256 + l * 8];
          acc1[ty] = mfma_(ax, wxv, acc1[ty]);
        }
      }
      const int u = wv * 16 + c;
      #pragma unroll
      for (int r = 0; r < 4; r++) {
        float ig = sigm(acc1[0][r]);
        float fg = sigm(acc1[1][r]);
        float gg = tanh_(acc1[2][r]);
        float og = sigm(acc1[3][r]);
        float cn = fg * c1[r] + ig * gg;
        float hn = og * tanh_(cn);
        c1[r] = cn;
        u16 hi = f2bf(hn);
        float lo = hn - bf2f(hi);
        const int row = (q * 4 + r) * X1S;
        Xn[row + u]       = hi;
        Xn[row + 128 + u] = f2bf(lo);
      }
    }
    __syncthreads();                   // end: h1(t), h2(t-1), x(t+1) published
  }
}

extern "C" void kernel_launch(void* const* d_in, const int* in_sizes, int n_in,
                              void* d_out, int out_size, void* d_ws, size_t ws_size,
                              hipStream_t stream) {
  (void)in_sizes; (void)n_in; (void)out_size; (void)d_ws; (void)ws_size;
  spc_lstm<<<dim3(256), dim3(512), 0, stream>>>(
      (const float*)d_in[0],  (const float*)d_in[1],
      (const float*)d_in[2],  (const float*)d_in[3],
      (const float*)d_in[4],  (const float*)d_in[5],
      (const float*)d_in[6],  (const float*)d_in[7],
      (const float*)d_in[8],  (const float*)d_in[9],
      (const float*)d_in[10], (const float*)d_in[11],
      (const float*)d_in[12], (const float*)d_in[13],
      (const float*)d_in[14], (float*)d_out);
}